// Round 8
// baseline (280.078 us; speedup 1.0000x reference)
//
#include <hip/hip_runtime.h>

#define N_NODES 50000
#define D_IN 256
#define D_OUT 128
#define N_POS 1600000
#define N_PRED 500000

#define G_BUCKETS 782        // ceil(50000/64) buckets of 64 nodes
#define GPAD 1024
#define SB 640               // scatter blocks
#define CHUNK 2500           // SB*CHUNK == N_POS exactly
#define CAP 4096             // per-bucket segment cap (mean 2048, sigma ~45)
#define GEMM_BLOCKS 782      // (N_NODES+63)/64
#define QPRED 125000         // N_PRED/4 — score_k processes 4 edges per 16-lane group

#define NT 4                 // source tiles: 12500 rows x 256B = 3.2 MB, fits 4 MiB per-XCD L2
#define TSZ 12500
#define NPB 32               // nodes per aggregation block (2 per 16-lane group)
#define AGGB 1563            // ceil(50000/32); ~6252 waves ≈ full residency

typedef __attribute__((ext_vector_type(8))) short short8;
typedef __attribute__((ext_vector_type(4))) float f32x4;

// ---- bf16 helpers (RNE) ----
__device__ __forceinline__ unsigned short f2bf(float f) {
    unsigned int u = __float_as_uint(f);
    u += 0x7FFFu + ((u >> 16) & 1u);
    return (unsigned short)(u >> 16);
}
__device__ __forceinline__ unsigned int pk2(float a, float b) {   // bf16(a) | bf16(b)<<16
    unsigned int ua = __float_as_uint(a), ub = __float_as_uint(b);
    ua += 0x7FFFu + ((ua >> 16) & 1u);
    ub += 0x7FFFu + ((ub >> 16) & 1u);
    return (ua >> 16) | (ub & 0xFFFF0000u);
}
__device__ __forceinline__ float bflo(unsigned int u) { return __uint_as_float(u << 16); }
__device__ __forceinline__ float bfhi(unsigned int u) { return __uint_as_float(u & 0xFFFF0000u); }

__device__ __forceinline__ float dot8(uint4 ua, uint4 ub) {
    return bflo(ua.x) * bflo(ub.x) + bfhi(ua.x) * bfhi(ub.x)
         + bflo(ua.y) * bflo(ub.y) + bfhi(ua.y) * bfhi(ub.y)
         + bflo(ua.z) * bflo(ub.z) + bfhi(ua.z) * bfhi(ub.z)
         + bflo(ua.w) * bflo(ub.w) + bfhi(ua.w) * bfhi(ub.w);
}

// ------- fused launch: blocks [0,SB) bucket-scatter (long jobs first);
//         blocks [SB, SB+128) weight-fuse Wf = W1@Wc into MFMA B-frag + bf = b1@Wc.
//         Scatter also accumulates deg[] via fire-and-forget global atomics. -------
__global__ __launch_bounds__(256) void scatter_fuse_k(const int* __restrict__ row,
                                                      const int* __restrict__ col,
                                                      unsigned int* __restrict__ seg,
                                                      unsigned int* __restrict__ ebs,
                                                      int* __restrict__ deg,
                                                      const float* __restrict__ W1,
                                                      const float* __restrict__ Wc,
                                                      const float* __restrict__ b1,
                                                      unsigned short* __restrict__ Bp,
                                                      float* __restrict__ bf) {
    __shared__ __align__(16) char smem[23424];
    if (blockIdx.x < SB) {
        // ---------------- scatter role ----------------
        int* hist  = (int*)smem;                 // GPAD ints
        int* lofs  = hist + GPAD;                // GPAD ints
        int* fill2 = lofs + GPAD;                // GPAD ints
        int* part  = fill2 + GPAD;               // 256 ints
        unsigned int* stag = (unsigned int*)(part + 256);   // CHUNK u32
        int t = threadIdx.x;
        int b = blockIdx.x;
        for (int i = t; i < GPAD; i += 256) { hist[i] = 0; fill2[i] = 0; }
        __syncthreads();
        int e0 = b * CHUNK;
        for (int i = t; i < CHUNK; i += 256) {
            int c = col[e0 + i];
            atomicAdd(&hist[c >> 6], 1);
            atomicAdd(&deg[c], 1);               // fire-and-forget, 50K addresses
        }
        __syncthreads();
        int h[4], p4 = 0;
        #pragma unroll
        for (int i = 0; i < 4; ++i) { h[i] = hist[4 * t + i]; p4 += h[i]; }
        part[t] = p4;
        __syncthreads();
        for (int d = 1; d < 256; d <<= 1) {
            int add = (t >= d) ? part[t - d] : 0;
            __syncthreads();
            part[t] += add;
            __syncthreads();
        }
        int ex = part[t] - p4;
        #pragma unroll
        for (int i = 0; i < 4; ++i) { lofs[4 * t + i] = ex; ex += h[i]; }
        __syncthreads();
        // deterministic segment table: (local offset, count) packed
        for (int g = t; g < G_BUCKETS; g += 256)
            seg[(long)g * SB + b] = (unsigned int)lofs[g] | ((unsigned int)hist[g] << 16);
        for (int i = t; i < CHUNK; i += 256) {
            int c = col[e0 + i];
            int g = c >> 6;
            unsigned int u = (unsigned int)row[e0 + i] | ((unsigned int)(c & 63) << 16);
            int lp = atomicAdd(&fill2[g], 1);
            stag[lofs[g] + lp] = u;
        }
        __syncthreads();
        // coalesced slab write
        for (int i = t; i < CHUNK; i += 256)
            ebs[(long)b * CHUNK + i] = stag[i];
    } else {
        // ---------------- weight-fuse role ----------------
        int gid = (blockIdx.x - SB) * 256 + threadIdx.x;   // 0..32767
        int k = gid >> 7;          // K dim
        int n = gid & 127;         // N dim
        float acc = 0.f;
        #pragma unroll 4
        for (int kk = 0; kk < D_IN; ++kk)
            acc += W1[k * D_IN + kk] * Wc[kk * D_OUT + n];
        int ks = k >> 5, q = (k >> 3) & 3, jj = k & 7;
        int nt = n >> 4, nl = n & 15;
        int lane = q * 16 + nl;
        Bp[(((long)(ks * 8 + nt)) * 64 + lane) * 8 + jj] = f2bf(acc);
        if (gid < D_OUT) {
            float accb = 0.f;
            for (int kk = 0; kk < D_IN; ++kk)
                accb += b1[kk] * Wc[kk * D_OUT + gid];
            bf[gid] = accb;
        }
    }
}

// ------- fused launch #2: blocks [0, G_BUCKETS) = CSR-build role (longer, first);
//         blocks [G_BUCKETS, ...) = MFMA gemm role writing PRE-SCALED rows
//         hsb[v] = dinv[v] * (x@Wf + bf)[v]  (fp32 scale, single bf16 rounding)
//         plus dinv[v] for the finalize. deg[] is complete from L1. -------
__global__ __launch_bounds__(256) void gemm_csr_k(const unsigned int* __restrict__ seg,
                                                  const unsigned int* __restrict__ ebs,
                                                  unsigned short* __restrict__ csr,
                                                  int* __restrict__ offs5,
                                                  const int* __restrict__ deg,
                                                  float* __restrict__ dinv,
                                                  const float* __restrict__ x,
                                                  const uint4* __restrict__ Bp,
                                                  const float* __restrict__ bf,
                                                  unsigned short* __restrict__ hsb) {
    __shared__ __align__(16) char smem[28704];
    if (blockIdx.x < G_BUCKETS) {
        // ---------------- CSR-build role ----------------
        unsigned int* stag = (unsigned int*)smem;                 // CAP u32   = 16384 B
        unsigned short* stag2 = (unsigned short*)(smem + 16384);  // CAP u16   =  8192 B
        int* hist = (int*)(smem + 24576);                         // 256 ints
        int* lofs = hist + 256;
        int* fill = lofs + 256;
        int* part = fill + 256;
        __shared__ int scnt;
        int t = threadIdx.x;
        int g = blockIdx.x;
        int s = g * CAP;
        hist[t] = 0; fill[t] = 0;
        // --- segment scan + gather: thread t owns origin-blocks t, t+256, t+512 ---
        const unsigned int* sg = seg + (long)g * SB;
        unsigned int w0 = sg[t];
        unsigned int w1 = sg[t + 256];
        unsigned int w2 = (t + 512 < SB) ? sg[t + 512] : 0u;
        int c0 = w0 >> 16, c1 = w1 >> 16, c2 = w2 >> 16;
        int lsum = c0 + c1 + c2;
        part[t] = lsum;
        __syncthreads();
        for (int d = 1; d < 256; d <<= 1) {
            int add = (t >= d) ? part[t - d] : 0;
            __syncthreads();
            part[t] += add;
            __syncthreads();
        }
        if (t == 255) scnt = part[255];
        int p = part[t] - lsum;
        {
            const unsigned int* e0p = ebs + (long)t * CHUNK + (w0 & 0xFFFFu);
            for (int k = 0; k < c0; ++k) stag[p + k] = e0p[k];
            p += c0;
            const unsigned int* e1p = ebs + (long)(t + 256) * CHUNK + (w1 & 0xFFFFu);
            for (int k = 0; k < c1; ++k) stag[p + k] = e1p[k];
            p += c1;
            const unsigned int* e2p = ebs + (long)(t + 512) * CHUNK + (w2 & 0xFFFFu);
            for (int k = 0; k < c2; ++k) stag[p + k] = e2p[k];
        }
        __syncthreads();
        int cnt = scnt;
        // --- 256-key histogram (node_low6, src_tile) over the staged bucket ---
        for (int i = t; i < cnt; i += 256) {
            unsigned int u = stag[i];
            int r = u & 0xFFFF;
            int tile = (r >= TSZ) + (r >= 2 * TSZ) + (r >= 3 * TSZ);
            atomicAdd(&hist[((u >> 16) & 63) * NT + tile], 1);
        }
        __syncthreads();
        int hv = hist[t];
        part[t] = hv;
        __syncthreads();
        for (int d = 1; d < 256; d <<= 1) {
            int add = (t >= d) ? part[t - d] : 0;
            __syncthreads();
            part[t] += add;
            __syncthreads();
        }
        lofs[t] = part[t] - hv;
        __syncthreads();
        if (t < 64) {
            int v = g * 64 + t;
            if (v < N_NODES) {
                int b4 = t * NT;
                int cc0 = hist[b4], cc1 = hist[b4 + 1], cc2 = hist[b4 + 2], cc3 = hist[b4 + 3];
                int o0 = s + lofs[b4];
                offs5[v * 5 + 0] = o0;
                offs5[v * 5 + 1] = o0 + cc0;
                offs5[v * 5 + 2] = o0 + cc0 + cc1;
                offs5[v * 5 + 3] = o0 + cc0 + cc1 + cc2;
                offs5[v * 5 + 4] = o0 + cc0 + cc1 + cc2 + cc3;
            }
        }
        for (int i = t; i < cnt; i += 256) {
            unsigned int u = stag[i];
            int r = u & 0xFFFF;
            int tile = (r >= TSZ) + (r >= 2 * TSZ) + (r >= 3 * TSZ);
            int key = ((u >> 16) & 63) * NT + tile;
            int lp = atomicAdd(&fill[key], 1);
            stag2[lofs[key] + lp] = (unsigned short)r;
        }
        __syncthreads();
        for (int i = t; i < cnt; i += 256)
            csr[s + i] = stag2[i];
    } else {
        // ---------------- gemm role: hsb = dinv .* (x@Wf + bf) ----------------
        const int gb   = blockIdx.x - G_BUCKETS;
        const int wave = threadIdx.x >> 6;
        const int lane = threadIdx.x & 63;
        const int q    = lane >> 4;
        const int ml   = lane & 15;
        const int m0   = gb * 64 + wave * 16;

        // emit dinv for this block's 64 rows (deg complete since L1)
        if (threadIdx.x < 64) {
            int v = gb * 64 + threadIdx.x;
            if (v < N_NODES) dinv[v] = rsqrtf((float)deg[v] + 1.0f);
        }

        f32x4 acc[8];
        #pragma unroll
        for (int t = 0; t < 8; ++t) acc[t] = (f32x4){0.f, 0.f, 0.f, 0.f};

        long arow = m0 + ml; if (arow > N_NODES - 1) arow = N_NODES - 1;
        const float* xrow = x + arow * D_IN + q * 8;

        #pragma unroll
        for (int ks = 0; ks < 8; ++ks) {
            float4 xa = *(const float4*)(xrow + ks * 32);
            float4 xb = *(const float4*)(xrow + ks * 32 + 4);
            union { short8 s; unsigned int u[4]; } af;
            af.u[0] = pk2(xa.x, xa.y);
            af.u[1] = pk2(xa.z, xa.w);
            af.u[2] = pk2(xb.x, xb.y);
            af.u[3] = pk2(xb.z, xb.w);
            #pragma unroll
            for (int nt = 0; nt < 8; ++nt) {
                union { uint4 v; short8 s; } bu;
                bu.v = Bp[(long)(ks * 8 + nt) * 64 + lane];
                acc[nt] = __builtin_amdgcn_mfma_f32_16x16x32_bf16(af.s, bu.s, acc[nt], 0, 0, 0);
            }
        }

        // per-row dinv (row = m0 + q*4 + r; deg array padded to 50048)
        float dr[4];
        #pragma unroll
        for (int r = 0; r < 4; ++r)
            dr[r] = rsqrtf((float)deg[m0 + q * 4 + r] + 1.0f);

        unsigned short* o = (unsigned short*)smem + wave * 2048;
        #pragma unroll
        for (int nt = 0; nt < 8; ++nt) {
            float bn = bf[nt * 16 + ml];
            #pragma unroll
            for (int r = 0; r < 4; ++r) {
                float val = (acc[nt][r] + bn) * dr[r];   // fp32 scale, one bf16 rounding
                o[(q * 4 + r) * 128 + nt * 16 + ml] = f2bf(val);
            }
        }
        __syncthreads();
        #pragma unroll
        for (int i = 0; i < 4; ++i) {
            int fb = i * 1024 + lane * 16;
            int v = m0 + (fb >> 8);
            if (v < N_NODES) {
                uint4 val = *(const uint4*)((const char*)o + fb);
                *(uint4*)((char*)hsb + (long)v * 256 + (fb & 255)) = val;
            }
        }
    }
}

// ---- source-tiled aggregation (R3 shape): 16-lane group owns 2 nodes; register
//      accumulators; hsb rows are pre-scaled -> pure bf16 row-sum loop. ----
__global__ __launch_bounds__(256, 8) void aggregate_csr_k(const int* __restrict__ offs5,
                                                          const unsigned short* __restrict__ csr,
                                                          const uint4* __restrict__ hs4,
                                                          const float* __restrict__ dinv,
                                                          const float* __restrict__ bc,
                                                          uint4* __restrict__ feat4) {
    int tid = threadIdx.x;
    int li  = tid & 15;
    int g16 = tid >> 4;                       // 0..15 group id in block
    int v0 = blockIdx.x * NPB + g16 * 2;
    int v1 = v0 + 1;
    bool ok0 = v0 < N_NODES, ok1 = v1 < N_NODES;

    float a0[8] = {0.f, 0.f, 0.f, 0.f, 0.f, 0.f, 0.f, 0.f};
    float a1[8] = {0.f, 0.f, 0.f, 0.f, 0.f, 0.f, 0.f, 0.f};

    #pragma unroll 1
    for (int tt = 0; tt < NT; ++tt) {
        if (ok0) {
            int i  = offs5[v0 * 5 + tt];
            int s1 = offs5[v0 * 5 + tt + 1];
            for (; i + 3 < s1; i += 4) {
                int r0 = csr[i], r1 = csr[i + 1], r2 = csr[i + 2], r3 = csr[i + 3];
                uint4 u0 = hs4[r0 * 16 + li];
                uint4 u1 = hs4[r1 * 16 + li];
                uint4 u2 = hs4[r2 * 16 + li];
                uint4 u3 = hs4[r3 * 16 + li];
                a0[0] += (bflo(u0.x) + bflo(u1.x)) + (bflo(u2.x) + bflo(u3.x));
                a0[1] += (bfhi(u0.x) + bfhi(u1.x)) + (bfhi(u2.x) + bfhi(u3.x));
                a0[2] += (bflo(u0.y) + bflo(u1.y)) + (bflo(u2.y) + bflo(u3.y));
                a0[3] += (bfhi(u0.y) + bfhi(u1.y)) + (bfhi(u2.y) + bfhi(u3.y));
                a0[4] += (bflo(u0.z) + bflo(u1.z)) + (bflo(u2.z) + bflo(u3.z));
                a0[5] += (bfhi(u0.z) + bfhi(u1.z)) + (bfhi(u2.z) + bfhi(u3.z));
                a0[6] += (bflo(u0.w) + bflo(u1.w)) + (bflo(u2.w) + bflo(u3.w));
                a0[7] += (bfhi(u0.w) + bfhi(u1.w)) + (bfhi(u2.w) + bfhi(u3.w));
            }
            for (; i < s1; ++i) {
                int r = csr[i];
                uint4 u = hs4[r * 16 + li];
                a0[0] += bflo(u.x); a0[1] += bfhi(u.x);
                a0[2] += bflo(u.y); a0[3] += bfhi(u.y);
                a0[4] += bflo(u.z); a0[5] += bfhi(u.z);
                a0[6] += bflo(u.w); a0[7] += bfhi(u.w);
            }
        }
        if (ok1) {
            int i  = offs5[v1 * 5 + tt];
            int s1 = offs5[v1 * 5 + tt + 1];
            for (; i + 3 < s1; i += 4) {
                int r0 = csr[i], r1 = csr[i + 1], r2 = csr[i + 2], r3 = csr[i + 3];
                uint4 u0 = hs4[r0 * 16 + li];
                uint4 u1 = hs4[r1 * 16 + li];
                uint4 u2 = hs4[r2 * 16 + li];
                uint4 u3 = hs4[r3 * 16 + li];
                a1[0] += (bflo(u0.x) + bflo(u1.x)) + (bflo(u2.x) + bflo(u3.x));
                a1[1] += (bfhi(u0.x) + bfhi(u1.x)) + (bfhi(u2.x) + bfhi(u3.x));
                a1[2] += (bflo(u0.y) + bflo(u1.y)) + (bflo(u2.y) + bflo(u3.y));
                a1[3] += (bfhi(u0.y) + bfhi(u1.y)) + (bfhi(u2.y) + bfhi(u3.y));
                a1[4] += (bflo(u0.z) + bflo(u1.z)) + (bflo(u2.z) + bflo(u3.z));
                a1[5] += (bfhi(u0.z) + bfhi(u1.z)) + (bfhi(u2.z) + bfhi(u3.z));
                a1[6] += (bflo(u0.w) + bflo(u1.w)) + (bflo(u2.w) + bflo(u3.w));
                a1[7] += (bfhi(u0.w) + bfhi(u1.w)) + (bfhi(u2.w) + bfhi(u3.w));
            }
            for (; i < s1; ++i) {
                int r = csr[i];
                uint4 u = hs4[r * 16 + li];
                a1[0] += bflo(u.x); a1[1] += bfhi(u.x);
                a1[2] += bflo(u.y); a1[3] += bfhi(u.y);
                a1[4] += bflo(u.z); a1[5] += bfhi(u.z);
                a1[6] += bflo(u.w); a1[7] += bfhi(u.w);
            }
        }
    }
    // finalize: out = dv*(sum + h_scaled_self) + bc   (h_scaled_self = dv*h_self)
    float4 b0 = *(const float4*)(bc + li * 8);
    float4 b1 = *(const float4*)(bc + li * 8 + 4);
    if (ok0) {
        uint4 su = hs4[(long)v0 * 16 + li];
        float dv = dinv[v0];
        float f0 = dv * (a0[0] + bflo(su.x)) + b0.x;
        float f1 = dv * (a0[1] + bfhi(su.x)) + b0.y;
        float f2 = dv * (a0[2] + bflo(su.y)) + b0.z;
        float f3 = dv * (a0[3] + bfhi(su.y)) + b0.w;
        float f4 = dv * (a0[4] + bflo(su.z)) + b1.x;
        float f5 = dv * (a0[5] + bfhi(su.z)) + b1.y;
        float f6 = dv * (a0[6] + bflo(su.w)) + b1.z;
        float f7 = dv * (a0[7] + bfhi(su.w)) + b1.w;
        uint4 o;
        o.x = pk2(f0, f1); o.y = pk2(f2, f3); o.z = pk2(f4, f5); o.w = pk2(f6, f7);
        feat4[(long)v0 * 16 + li] = o;
    }
    if (ok1) {
        uint4 su = hs4[(long)v1 * 16 + li];
        float dv = dinv[v1];
        float f0 = dv * (a1[0] + bflo(su.x)) + b0.x;
        float f1 = dv * (a1[1] + bfhi(su.x)) + b0.y;
        float f2 = dv * (a1[2] + bflo(su.y)) + b0.z;
        float f3 = dv * (a1[3] + bfhi(su.y)) + b0.w;
        float f4 = dv * (a1[4] + bflo(su.z)) + b1.x;
        float f5 = dv * (a1[5] + bfhi(su.z)) + b1.y;
        float f6 = dv * (a1[6] + bflo(su.w)) + b1.z;
        float f7 = dv * (a1[7] + bfhi(su.w)) + b1.w;
        uint4 o;
        o.x = pk2(f0, f1); o.y = pk2(f2, f3); o.z = pk2(f4, f5); o.w = pk2(f6, f7);
        feat4[(long)v1 * 16 + li] = o;
    }
}

// ---------------- logits[e] = dot(feat[src], feat[dst]) — 16 lanes/edge ----------------
__global__ void score_k(const int* __restrict__ src, const int* __restrict__ dst,
                        const uint4* __restrict__ feat4, float* __restrict__ out) {
    int gid = blockIdx.x * blockDim.x + threadIdx.x;
    int e = gid >> 4;
    int c = gid & 15;
    if (e >= QPRED) return;
    int e0 = e, e1 = e + QPRED, e2 = e + 2 * QPRED, e3 = e + 3 * QPRED;
    int a0 = src[e0], b0 = dst[e0];
    int a1 = src[e1], b1 = dst[e1];
    int a2 = src[e2], b2 = dst[e2];
    int a3 = src[e3], b3 = dst[e3];
    uint4 ua0 = feat4[(long)a0 * 16 + c];
    uint4 ub0 = feat4[(long)b0 * 16 + c];
    uint4 ua1 = feat4[(long)a1 * 16 + c];
    uint4 ub1 = feat4[(long)b1 * 16 + c];
    uint4 ua2 = feat4[(long)a2 * 16 + c];
    uint4 ub2 = feat4[(long)b2 * 16 + c];
    uint4 ua3 = feat4[(long)a3 * 16 + c];
    uint4 ub3 = feat4[(long)b3 * 16 + c];
    float p0 = dot8(ua0, ub0);
    float p1 = dot8(ua1, ub1);
    float p2 = dot8(ua2, ub2);
    float p3 = dot8(ua3, ub3);
    #pragma unroll
    for (int m = 8; m; m >>= 1) {
        p0 += __shfl_xor(p0, m, 16);
        p1 += __shfl_xor(p1, m, 16);
        p2 += __shfl_xor(p2, m, 16);
        p3 += __shfl_xor(p3, m, 16);
    }
    if (c == 0) {
        out[e0] = p0;
        out[e1] = p1;
        out[e2] = p2;
        out[e3] = p3;
    }
}

extern "C" void kernel_launch(void* const* d_in, const int* in_sizes, int n_in,
                              void* d_out, int out_size, void* d_ws, size_t ws_size,
                              hipStream_t stream) {
    const float* x   = (const float*)d_in[0];
    const int*   ei  = (const int*)  d_in[1];   // [2, N_PRED]
    const int*   pe  = (const int*)  d_in[2];   // [2, N_POS]
    const float* W1  = (const float*)d_in[3];
    const float* b1  = (const float*)d_in[4];
    const float* Wc  = (const float*)d_in[5];
    const float* bc  = (const float*)d_in[6];
    float* out = (float*)d_out;

    const int* pe_row = pe;            // source
    const int* pe_col = pe + N_POS;    // target (aggregation)
    const int* ei_src = ei;
    const int* ei_dst = ei + N_PRED;

    // workspace layout (16B-aligned blocks)
    char* w = (char*)d_ws;
    unsigned short* Bp = (unsigned short*)w;  w += 32768 * 2;      // 64 KB
    float* bf    = (float*)w;                 w += 128 * 4;
    float* dinv  = (float*)w;                 w += 50000 * 4;
    int*   deg   = (int*)w;                   w += 50048 * 4;      // padded past N_NODES
    int*   offs5 = (int*)w;                   w += 50000 * 5 * 4;  // 1 MB
    unsigned int* seg = (unsigned int*)w;     w += (long)G_BUCKETS * SB * 4;     // 2.0 MB
    unsigned int* ebs = (unsigned int*)w;     w += (long)SB * CHUNK * 4;         // 6.4 MB
    unsigned short* csr = (unsigned short*)w; w += (long)G_BUCKETS * CAP * 2;    // 6.4 MB
    unsigned short* hsb   = (unsigned short*)w;  w += (long)N_NODES * D_OUT * 2; // 12.8 MB
    unsigned short* featb = (unsigned short*)w;  // 12.8 MB

    // L0: zero degree counters (capture-safe async memset)
    hipMemsetAsync(deg, 0, 50048 * sizeof(int), stream);

    // L1: scatter + deg atomics (640 blocks) || weight fuse (128 blocks)
    scatter_fuse_k<<<SB + 128, 256, 0, stream>>>(pe_row, pe_col, seg, ebs, deg,
                                                 W1, Wc, b1, Bp, bf);

    // L2: CSR build (782 blocks, first) || MFMA gemm writing pre-scaled hsb + dinv
    gemm_csr_k    <<<G_BUCKETS + GEMM_BLOCKS, 256, 0, stream>>>(seg, ebs, csr, offs5,
                                                                deg, dinv, x,
                                                                (const uint4*)Bp, bf, hsb);

    // L3: source-tiled aggregation + finalize (pure row-sum loop)
    aggregate_csr_k<<<AGGB, 256, 0, stream>>>(offs5, csr, (const uint4*)hsb,
                                              dinv, bc, (uint4*)featb);

    // L4: scoring — 4 edges per 16-lane group
    score_k       <<<(QPRED * 16 + 255) / 256, 256, 0, stream>>>(
                      ei_src, ei_dst, (const uint4*)featb, out);
}

// Round 9
// 231.715 us; speedup vs baseline: 1.2087x; 1.2087x over previous
//
#include <hip/hip_runtime.h>

#define N_NODES 50000
#define D_IN 256
#define D_OUT 128
#define N_POS 1600000
#define N_PRED 500000

#define G_BUCKETS 782        // ceil(50000/64) buckets of 64 nodes
#define GPAD 1024
#define SB 1280              // scatter blocks (doubled: halves per-block serial chain)
#define CHUNK 1250           // SB*CHUNK == N_POS exactly
#define CAP 4096             // per-bucket segment cap (mean 2048, sigma ~45)
#define GEMM_BLOCKS 782      // (N_NODES+63)/64
#define QPRED 125000         // N_PRED/4 — score_k processes 4 edges per 16-lane group

#define NT 4                 // source tiles: 12500 rows x 256B = 3.2 MB, fits 4 MiB per-XCD L2
#define TSZ 12500
#define NPB 32               // nodes per aggregation block (2 per 16-lane group)
#define AGGB 1563            // ceil(50000/32); ~6252 waves ≈ full residency

typedef __attribute__((ext_vector_type(8))) short short8;
typedef __attribute__((ext_vector_type(4))) float f32x4;

// ---- bf16 helpers (RNE) ----
__device__ __forceinline__ unsigned short f2bf(float f) {
    unsigned int u = __float_as_uint(f);
    u += 0x7FFFu + ((u >> 16) & 1u);
    return (unsigned short)(u >> 16);
}
__device__ __forceinline__ unsigned int pk2(float a, float b) {   // bf16(a) | bf16(b)<<16
    unsigned int ua = __float_as_uint(a), ub = __float_as_uint(b);
    ua += 0x7FFFu + ((ua >> 16) & 1u);
    ub += 0x7FFFu + ((ub >> 16) & 1u);
    return (ua >> 16) | (ub & 0xFFFF0000u);
}
__device__ __forceinline__ float bflo(unsigned int u) { return __uint_as_float(u << 16); }
__device__ __forceinline__ float bfhi(unsigned int u) { return __uint_as_float(u & 0xFFFF0000u); }

__device__ __forceinline__ float dot8(uint4 ua, uint4 ub) {
    return bflo(ua.x) * bflo(ub.x) + bfhi(ua.x) * bfhi(ub.x)
         + bflo(ua.y) * bflo(ub.y) + bfhi(ua.y) * bfhi(ub.y)
         + bflo(ua.z) * bflo(ub.z) + bfhi(ua.z) * bfhi(ub.z)
         + bflo(ua.w) * bflo(ub.w) + bfhi(ua.w) * bfhi(ub.w);
}

// ------- fused launch: blocks [0,SB) bucket-scatter (long jobs first);
//         blocks [SB, SB+128) weight-fuse Wf = W1@Wc into MFMA B-frag + bf = b1@Wc.
//         NO global atomics anywhere. 18.4 KB smem -> 8 blocks/CU. -------
__global__ __launch_bounds__(256) void scatter_fuse_k(const int* __restrict__ row,
                                                      const int* __restrict__ col,
                                                      unsigned int* __restrict__ seg,
                                                      unsigned int* __restrict__ ebs,
                                                      const float* __restrict__ W1,
                                                      const float* __restrict__ Wc,
                                                      const float* __restrict__ b1,
                                                      unsigned short* __restrict__ Bp,
                                                      float* __restrict__ bf) {
    __shared__ __align__(16) char smem[18432];
    if (blockIdx.x < SB) {
        // ---------------- scatter role ----------------
        int* hist  = (int*)smem;                 // GPAD ints
        int* lofs  = hist + GPAD;                // GPAD ints
        int* fill2 = lofs + GPAD;                // GPAD ints
        int* part  = fill2 + GPAD;               // 256 ints
        unsigned int* stag = (unsigned int*)(part + 256);   // CHUNK u32 (5000 B)
        int t = threadIdx.x;
        int b = blockIdx.x;
        for (int i = t; i < GPAD; i += 256) { hist[i] = 0; fill2[i] = 0; }
        __syncthreads();
        int e0 = b * CHUNK;
        for (int i = t; i < CHUNK; i += 256)
            atomicAdd(&hist[col[e0 + i] >> 6], 1);
        __syncthreads();
        int h[4], p4 = 0;
        #pragma unroll
        for (int i = 0; i < 4; ++i) { h[i] = hist[4 * t + i]; p4 += h[i]; }
        part[t] = p4;
        __syncthreads();
        for (int d = 1; d < 256; d <<= 1) {
            int add = (t >= d) ? part[t - d] : 0;
            __syncthreads();
            part[t] += add;
            __syncthreads();
        }
        int ex = part[t] - p4;
        #pragma unroll
        for (int i = 0; i < 4; ++i) { lofs[4 * t + i] = ex; ex += h[i]; }
        __syncthreads();
        // deterministic segment table: (local offset, count) packed
        for (int g = t; g < G_BUCKETS; g += 256)
            seg[(long)g * SB + b] = (unsigned int)lofs[g] | ((unsigned int)hist[g] << 16);
        for (int i = t; i < CHUNK; i += 256) {
            int c = col[e0 + i];
            int g = c >> 6;
            unsigned int u = (unsigned int)row[e0 + i] | ((unsigned int)(c & 63) << 16);
            int lp = atomicAdd(&fill2[g], 1);
            stag[lofs[g] + lp] = u;
        }
        __syncthreads();
        // coalesced slab write
        for (int i = t; i < CHUNK; i += 256)
            ebs[(long)b * CHUNK + i] = stag[i];
    } else {
        // ---------------- weight-fuse role ----------------
        int gid = (blockIdx.x - SB) * 256 + threadIdx.x;   // 0..32767
        int k = gid >> 7;          // K dim
        int n = gid & 127;         // N dim
        float acc = 0.f;
        #pragma unroll 4
        for (int kk = 0; kk < D_IN; ++kk)
            acc += W1[k * D_IN + kk] * Wc[kk * D_OUT + n];
        int ks = k >> 5, q = (k >> 3) & 3, jj = k & 7;
        int nt = n >> 4, nl = n & 15;
        int lane = q * 16 + nl;
        Bp[(((long)(ks * 8 + nt)) * 64 + lane) * 8 + jj] = f2bf(acc);
        if (gid < D_OUT) {
            float accb = 0.f;
            for (int kk = 0; kk < D_IN; ++kk)
                accb += b1[kk] * Wc[kk * D_OUT + gid];
            bf[gid] = accb;
        }
    }
}

// ------- fused launch #2: blocks [0, G_BUCKETS) = CSR-build role (longer, first);
//         blocks [G_BUCKETS, G_BUCKETS+GEMM_BLOCKS) = MFMA gemm role.
//         Roles independent: csr needs seg/ebs; gemm needs Bp/bf/x. -------
__global__ __launch_bounds__(256) void gemm_csr_k(const unsigned int* __restrict__ seg,
                                                  const unsigned int* __restrict__ ebs,
                                                  unsigned short* __restrict__ csr,
                                                  int* __restrict__ offs5,
                                                  float* __restrict__ dinv,
                                                  const float* __restrict__ x,
                                                  const uint4* __restrict__ Bp,
                                                  const float* __restrict__ bf,
                                                  unsigned short* __restrict__ hsb) {
    __shared__ __align__(16) char smem[28704];
    if (blockIdx.x < G_BUCKETS) {
        // ---------------- CSR-build role ----------------
        unsigned int* stag = (unsigned int*)smem;                 // CAP u32   = 16384 B
        unsigned short* stag2 = (unsigned short*)(smem + 16384);  // CAP u16   =  8192 B
        int* hist = (int*)(smem + 24576);                         // 256 ints
        int* lofs = hist + 256;
        int* fill = lofs + 256;
        int* part = fill + 256;
        __shared__ int scnt;
        int t = threadIdx.x;
        int g = blockIdx.x;
        int s = g * CAP;
        hist[t] = 0; fill[t] = 0;
        // --- segment scan + gather: thread t owns origin-blocks t+256*k, k=0..4 ---
        const unsigned int* sg = seg + (long)g * SB;
        unsigned int w0 = sg[t];
        unsigned int w1 = sg[t + 256];
        unsigned int w2 = sg[t + 512];
        unsigned int w3 = sg[t + 768];
        unsigned int w4 = sg[t + 1024];
        int c0 = w0 >> 16, c1 = w1 >> 16, c2 = w2 >> 16, c3 = w3 >> 16, c4 = w4 >> 16;
        int lsum = c0 + c1 + c2 + c3 + c4;
        part[t] = lsum;
        __syncthreads();
        for (int d = 1; d < 256; d <<= 1) {
            int add = (t >= d) ? part[t - d] : 0;
            __syncthreads();
            part[t] += add;
            __syncthreads();
        }
        if (t == 255) scnt = part[255];
        int p = part[t] - lsum;
        {
            const unsigned int* e0p = ebs + (long)t * CHUNK + (w0 & 0xFFFFu);
            for (int k = 0; k < c0; ++k) stag[p + k] = e0p[k];
            p += c0;
            const unsigned int* e1p = ebs + (long)(t + 256) * CHUNK + (w1 & 0xFFFFu);
            for (int k = 0; k < c1; ++k) stag[p + k] = e1p[k];
            p += c1;
            const unsigned int* e2p = ebs + (long)(t + 512) * CHUNK + (w2 & 0xFFFFu);
            for (int k = 0; k < c2; ++k) stag[p + k] = e2p[k];
            p += c2;
            const unsigned int* e3p = ebs + (long)(t + 768) * CHUNK + (w3 & 0xFFFFu);
            for (int k = 0; k < c3; ++k) stag[p + k] = e3p[k];
            p += c3;
            const unsigned int* e4p = ebs + (long)(t + 1024) * CHUNK + (w4 & 0xFFFFu);
            for (int k = 0; k < c4; ++k) stag[p + k] = e4p[k];
        }
        __syncthreads();
        int cnt = scnt;
        // --- 256-key histogram (node_low6, src_tile) over the staged bucket ---
        for (int i = t; i < cnt; i += 256) {
            unsigned int u = stag[i];
            int r = u & 0xFFFF;
            int tile = (r >= TSZ) + (r >= 2 * TSZ) + (r >= 3 * TSZ);
            atomicAdd(&hist[((u >> 16) & 63) * NT + tile], 1);
        }
        __syncthreads();
        int hv = hist[t];
        part[t] = hv;
        __syncthreads();
        for (int d = 1; d < 256; d <<= 1) {
            int add = (t >= d) ? part[t - d] : 0;
            __syncthreads();
            part[t] += add;
            __syncthreads();
        }
        lofs[t] = part[t] - hv;
        __syncthreads();
        if (t < 64) {
            int v = g * 64 + t;
            if (v < N_NODES) {
                int b4 = t * NT;
                int cc0 = hist[b4], cc1 = hist[b4 + 1], cc2 = hist[b4 + 2], cc3 = hist[b4 + 3];
                int o0 = s + lofs[b4];
                offs5[v * 5 + 0] = o0;
                offs5[v * 5 + 1] = o0 + cc0;
                offs5[v * 5 + 2] = o0 + cc0 + cc1;
                offs5[v * 5 + 3] = o0 + cc0 + cc1 + cc2;
                offs5[v * 5 + 4] = o0 + cc0 + cc1 + cc2 + cc3;
                dinv[v] = rsqrtf((float)(cc0 + cc1 + cc2 + cc3) + 1.0f);   // +1 self loop
            }
        }
        for (int i = t; i < cnt; i += 256) {
            unsigned int u = stag[i];
            int r = u & 0xFFFF;
            int tile = (r >= TSZ) + (r >= 2 * TSZ) + (r >= 3 * TSZ);
            int key = ((u >> 16) & 63) * NT + tile;
            int lp = atomicAdd(&fill[key], 1);
            stag2[lofs[key] + lp] = (unsigned short)r;
        }
        __syncthreads();
        for (int i = t; i < cnt; i += 256)
            csr[s + i] = stag2[i];
    } else {
        // ---------------- gemm role: h = x@Wf + bf (raw, UNscaled) ----------------
        const int gb   = blockIdx.x - G_BUCKETS;
        const int wave = threadIdx.x >> 6;
        const int lane = threadIdx.x & 63;
        const int q    = lane >> 4;
        const int ml   = lane & 15;
        const int m0   = gb * 64 + wave * 16;

        f32x4 acc[8];
        #pragma unroll
        for (int t = 0; t < 8; ++t) acc[t] = (f32x4){0.f, 0.f, 0.f, 0.f};

        long arow = m0 + ml; if (arow > N_NODES - 1) arow = N_NODES - 1;
        const float* xrow = x + arow * D_IN + q * 8;

        #pragma unroll
        for (int ks = 0; ks < 8; ++ks) {
            float4 xa = *(const float4*)(xrow + ks * 32);
            float4 xb = *(const float4*)(xrow + ks * 32 + 4);
            union { short8 s; unsigned int u[4]; } af;
            af.u[0] = pk2(xa.x, xa.y);
            af.u[1] = pk2(xa.z, xa.w);
            af.u[2] = pk2(xb.x, xb.y);
            af.u[3] = pk2(xb.z, xb.w);
            #pragma unroll
            for (int nt = 0; nt < 8; ++nt) {
                union { uint4 v; short8 s; } bu;
                bu.v = Bp[(long)(ks * 8 + nt) * 64 + lane];
                acc[nt] = __builtin_amdgcn_mfma_f32_16x16x32_bf16(af.s, bu.s, acc[nt], 0, 0, 0);
            }
        }

        unsigned short* o = (unsigned short*)smem + wave * 2048;
        #pragma unroll
        for (int nt = 0; nt < 8; ++nt) {
            float bn = bf[nt * 16 + ml];
            #pragma unroll
            for (int r = 0; r < 4; ++r) {
                float val = acc[nt][r] + bn;
                o[(q * 4 + r) * 128 + nt * 16 + ml] = f2bf(val);
            }
        }
        __syncthreads();
        #pragma unroll
        for (int i = 0; i < 4; ++i) {
            int fb = i * 1024 + lane * 16;
            int v = m0 + (fb >> 8);
            if (v < N_NODES) {
                uint4 val = *(const uint4*)((const char*)o + fb);
                *(uint4*)((char*)hsb + (long)v * 256 + (fb & 255)) = val;
            }
        }
    }
}

// ---- source-tiled aggregation (R3 shape): 16-lane group owns 2 nodes; register
//      accumulators; dinv[r] applied on the fly via fmaf. ----
__global__ __launch_bounds__(256, 8) void aggregate_csr_k(const int* __restrict__ offs5,
                                                          const unsigned short* __restrict__ csr,
                                                          const uint4* __restrict__ hs4,
                                                          const float* __restrict__ dinv,
                                                          const float* __restrict__ bc,
                                                          uint4* __restrict__ feat4) {
    int tid = threadIdx.x;
    int li  = tid & 15;
    int g16 = tid >> 4;                       // 0..15 group id in block
    int v0 = blockIdx.x * NPB + g16 * 2;
    int v1 = v0 + 1;
    bool ok0 = v0 < N_NODES, ok1 = v1 < N_NODES;

    float a0[8] = {0.f, 0.f, 0.f, 0.f, 0.f, 0.f, 0.f, 0.f};
    float a1[8] = {0.f, 0.f, 0.f, 0.f, 0.f, 0.f, 0.f, 0.f};

    #pragma unroll 1
    for (int tt = 0; tt < NT; ++tt) {
        if (ok0) {
            int i  = offs5[v0 * 5 + tt];
            int s1 = offs5[v0 * 5 + tt + 1];
            for (; i + 3 < s1; i += 4) {
                int r0 = csr[i], r1 = csr[i + 1], r2 = csr[i + 2], r3 = csr[i + 3];
                uint4 u0 = hs4[r0 * 16 + li];
                uint4 u1 = hs4[r1 * 16 + li];
                uint4 u2 = hs4[r2 * 16 + li];
                uint4 u3 = hs4[r3 * 16 + li];
                float d0 = dinv[r0], d1 = dinv[r1], d2 = dinv[r2], d3 = dinv[r3];
                a0[0] = fmaf(d0, bflo(u0.x), a0[0]); a0[0] = fmaf(d1, bflo(u1.x), a0[0]);
                a0[0] = fmaf(d2, bflo(u2.x), a0[0]); a0[0] = fmaf(d3, bflo(u3.x), a0[0]);
                a0[1] = fmaf(d0, bfhi(u0.x), a0[1]); a0[1] = fmaf(d1, bfhi(u1.x), a0[1]);
                a0[1] = fmaf(d2, bfhi(u2.x), a0[1]); a0[1] = fmaf(d3, bfhi(u3.x), a0[1]);
                a0[2] = fmaf(d0, bflo(u0.y), a0[2]); a0[2] = fmaf(d1, bflo(u1.y), a0[2]);
                a0[2] = fmaf(d2, bflo(u2.y), a0[2]); a0[2] = fmaf(d3, bflo(u3.y), a0[2]);
                a0[3] = fmaf(d0, bfhi(u0.y), a0[3]); a0[3] = fmaf(d1, bfhi(u1.y), a0[3]);
                a0[3] = fmaf(d2, bfhi(u2.y), a0[3]); a0[3] = fmaf(d3, bfhi(u3.y), a0[3]);
                a0[4] = fmaf(d0, bflo(u0.z), a0[4]); a0[4] = fmaf(d1, bflo(u1.z), a0[4]);
                a0[4] = fmaf(d2, bflo(u2.z), a0[4]); a0[4] = fmaf(d3, bflo(u3.z), a0[4]);
                a0[5] = fmaf(d0, bfhi(u0.z), a0[5]); a0[5] = fmaf(d1, bfhi(u1.z), a0[5]);
                a0[5] = fmaf(d2, bfhi(u2.z), a0[5]); a0[5] = fmaf(d3, bfhi(u3.z), a0[5]);
                a0[6] = fmaf(d0, bflo(u0.w), a0[6]); a0[6] = fmaf(d1, bflo(u1.w), a0[6]);
                a0[6] = fmaf(d2, bflo(u2.w), a0[6]); a0[6] = fmaf(d3, bflo(u3.w), a0[6]);
                a0[7] = fmaf(d0, bfhi(u0.w), a0[7]); a0[7] = fmaf(d1, bfhi(u1.w), a0[7]);
                a0[7] = fmaf(d2, bfhi(u2.w), a0[7]); a0[7] = fmaf(d3, bfhi(u3.w), a0[7]);
            }
            for (; i < s1; ++i) {
                int r = csr[i];
                uint4 u = hs4[r * 16 + li];
                float d = dinv[r];
                a0[0] = fmaf(d, bflo(u.x), a0[0]); a0[1] = fmaf(d, bfhi(u.x), a0[1]);
                a0[2] = fmaf(d, bflo(u.y), a0[2]); a0[3] = fmaf(d, bfhi(u.y), a0[3]);
                a0[4] = fmaf(d, bflo(u.z), a0[4]); a0[5] = fmaf(d, bfhi(u.z), a0[5]);
                a0[6] = fmaf(d, bflo(u.w), a0[6]); a0[7] = fmaf(d, bfhi(u.w), a0[7]);
            }
        }
        if (ok1) {
            int i  = offs5[v1 * 5 + tt];
            int s1 = offs5[v1 * 5 + tt + 1];
            for (; i + 3 < s1; i += 4) {
                int r0 = csr[i], r1 = csr[i + 1], r2 = csr[i + 2], r3 = csr[i + 3];
                uint4 u0 = hs4[r0 * 16 + li];
                uint4 u1 = hs4[r1 * 16 + li];
                uint4 u2 = hs4[r2 * 16 + li];
                uint4 u3 = hs4[r3 * 16 + li];
                float d0 = dinv[r0], d1 = dinv[r1], d2 = dinv[r2], d3 = dinv[r3];
                a1[0] = fmaf(d0, bflo(u0.x), a1[0]); a1[0] = fmaf(d1, bflo(u1.x), a1[0]);
                a1[0] = fmaf(d2, bflo(u2.x), a1[0]); a1[0] = fmaf(d3, bflo(u3.x), a1[0]);
                a1[1] = fmaf(d0, bfhi(u0.x), a1[1]); a1[1] = fmaf(d1, bfhi(u1.x), a1[1]);
                a1[1] = fmaf(d2, bfhi(u2.x), a1[1]); a1[1] = fmaf(d3, bfhi(u3.x), a1[1]);
                a1[2] = fmaf(d0, bflo(u0.y), a1[2]); a1[2] = fmaf(d1, bflo(u1.y), a1[2]);
                a1[2] = fmaf(d2, bflo(u2.y), a1[2]); a1[2] = fmaf(d3, bflo(u3.y), a1[2]);
                a1[3] = fmaf(d0, bfhi(u0.y), a1[3]); a1[3] = fmaf(d1, bfhi(u1.y), a1[3]);
                a1[3] = fmaf(d2, bfhi(u2.y), a1[3]); a1[3] = fmaf(d3, bfhi(u3.y), a1[3]);
                a1[4] = fmaf(d0, bflo(u0.z), a1[4]); a1[4] = fmaf(d1, bflo(u1.z), a1[4]);
                a1[4] = fmaf(d2, bflo(u2.z), a1[4]); a1[4] = fmaf(d3, bflo(u3.z), a1[4]);
                a1[5] = fmaf(d0, bfhi(u0.z), a1[5]); a1[5] = fmaf(d1, bfhi(u1.z), a1[5]);
                a1[5] = fmaf(d2, bfhi(u2.z), a1[5]); a1[5] = fmaf(d3, bfhi(u3.z), a1[5]);
                a1[6] = fmaf(d0, bflo(u0.w), a1[6]); a1[6] = fmaf(d1, bflo(u1.w), a1[6]);
                a1[6] = fmaf(d2, bflo(u2.w), a1[6]); a1[6] = fmaf(d3, bflo(u3.w), a1[6]);
                a1[7] = fmaf(d0, bfhi(u0.w), a1[7]); a1[7] = fmaf(d1, bfhi(u1.w), a1[7]);
                a1[7] = fmaf(d2, bfhi(u2.w), a1[7]); a1[7] = fmaf(d3, bfhi(u3.w), a1[7]);
            }
            for (; i < s1; ++i) {
                int r = csr[i];
                uint4 u = hs4[r * 16 + li];
                float d = dinv[r];
                a1[0] = fmaf(d, bflo(u.x), a1[0]); a1[1] = fmaf(d, bfhi(u.x), a1[1]);
                a1[2] = fmaf(d, bflo(u.y), a1[2]); a1[3] = fmaf(d, bfhi(u.y), a1[3]);
                a1[4] = fmaf(d, bflo(u.z), a1[4]); a1[5] = fmaf(d, bfhi(u.z), a1[5]);
                a1[6] = fmaf(d, bflo(u.w), a1[6]); a1[7] = fmaf(d, bfhi(u.w), a1[7]);
            }
        }
    }
    // finalize: out = dv*(sum + dv*h_self) + bc
    float4 b0 = *(const float4*)(bc + li * 8);
    float4 b1 = *(const float4*)(bc + li * 8 + 4);
    if (ok0) {
        uint4 su = hs4[(long)v0 * 16 + li];
        float dv = dinv[v0];
        float f0 = dv * (a0[0] + dv * bflo(su.x)) + b0.x;
        float f1 = dv * (a0[1] + dv * bfhi(su.x)) + b0.y;
        float f2 = dv * (a0[2] + dv * bflo(su.y)) + b0.z;
        float f3 = dv * (a0[3] + dv * bfhi(su.y)) + b0.w;
        float f4 = dv * (a0[4] + dv * bflo(su.z)) + b1.x;
        float f5 = dv * (a0[5] + dv * bfhi(su.z)) + b1.y;
        float f6 = dv * (a0[6] + dv * bflo(su.w)) + b1.z;
        float f7 = dv * (a0[7] + dv * bfhi(su.w)) + b1.w;
        uint4 o;
        o.x = pk2(f0, f1); o.y = pk2(f2, f3); o.z = pk2(f4, f5); o.w = pk2(f6, f7);
        feat4[(long)v0 * 16 + li] = o;
    }
    if (ok1) {
        uint4 su = hs4[(long)v1 * 16 + li];
        float dv = dinv[v1];
        float f0 = dv * (a1[0] + dv * bflo(su.x)) + b0.x;
        float f1 = dv * (a1[1] + dv * bfhi(su.x)) + b0.y;
        float f2 = dv * (a1[2] + dv * bflo(su.y)) + b0.z;
        float f3 = dv * (a1[3] + dv * bfhi(su.y)) + b0.w;
        float f4 = dv * (a1[4] + dv * bflo(su.z)) + b1.x;
        float f5 = dv * (a1[5] + dv * bfhi(su.z)) + b1.y;
        float f6 = dv * (a1[6] + dv * bflo(su.w)) + b1.z;
        float f7 = dv * (a1[7] + dv * bfhi(su.w)) + b1.w;
        uint4 o;
        o.x = pk2(f0, f1); o.y = pk2(f2, f3); o.z = pk2(f4, f5); o.w = pk2(f6, f7);
        feat4[(long)v1 * 16 + li] = o;
    }
}

// ---------------- logits[e] = dot(feat[src], feat[dst]) — 16 lanes/edge ----------------
__global__ void score_k(const int* __restrict__ src, const int* __restrict__ dst,
                        const uint4* __restrict__ feat4, float* __restrict__ out) {
    int gid = blockIdx.x * blockDim.x + threadIdx.x;
    int e = gid >> 4;
    int c = gid & 15;
    if (e >= QPRED) return;
    int e0 = e, e1 = e + QPRED, e2 = e + 2 * QPRED, e3 = e + 3 * QPRED;
    int a0 = src[e0], b0 = dst[e0];
    int a1 = src[e1], b1 = dst[e1];
    int a2 = src[e2], b2 = dst[e2];
    int a3 = src[e3], b3 = dst[e3];
    uint4 ua0 = feat4[(long)a0 * 16 + c];
    uint4 ub0 = feat4[(long)b0 * 16 + c];
    uint4 ua1 = feat4[(long)a1 * 16 + c];
    uint4 ub1 = feat4[(long)b1 * 16 + c];
    uint4 ua2 = feat4[(long)a2 * 16 + c];
    uint4 ub2 = feat4[(long)b2 * 16 + c];
    uint4 ua3 = feat4[(long)a3 * 16 + c];
    uint4 ub3 = feat4[(long)b3 * 16 + c];
    float p0 = dot8(ua0, ub0);
    float p1 = dot8(ua1, ub1);
    float p2 = dot8(ua2, ub2);
    float p3 = dot8(ua3, ub3);
    #pragma unroll
    for (int m = 8; m; m >>= 1) {
        p0 += __shfl_xor(p0, m, 16);
        p1 += __shfl_xor(p1, m, 16);
        p2 += __shfl_xor(p2, m, 16);
        p3 += __shfl_xor(p3, m, 16);
    }
    if (c == 0) {
        out[e0] = p0;
        out[e1] = p1;
        out[e2] = p2;
        out[e3] = p3;
    }
}

extern "C" void kernel_launch(void* const* d_in, const int* in_sizes, int n_in,
                              void* d_out, int out_size, void* d_ws, size_t ws_size,
                              hipStream_t stream) {
    const float* x   = (const float*)d_in[0];
    const int*   ei  = (const int*)  d_in[1];   // [2, N_PRED]
    const int*   pe  = (const int*)  d_in[2];   // [2, N_POS]
    const float* W1  = (const float*)d_in[3];
    const float* b1  = (const float*)d_in[4];
    const float* Wc  = (const float*)d_in[5];
    const float* bc  = (const float*)d_in[6];
    float* out = (float*)d_out;

    const int* pe_row = pe;            // source
    const int* pe_col = pe + N_POS;    // target (aggregation)
    const int* ei_src = ei;
    const int* ei_dst = ei + N_PRED;

    // workspace layout (16B-aligned blocks)
    char* w = (char*)d_ws;
    unsigned short* Bp = (unsigned short*)w;  w += 32768 * 2;      // 64 KB
    float* bf    = (float*)w;                 w += 128 * 4;
    float* dinv  = (float*)w;                 w += 50000 * 4;
    int*   offs5 = (int*)w;                   w += 50000 * 5 * 4;  // 1 MB
    unsigned int* seg = (unsigned int*)w;     w += (long)G_BUCKETS * SB * 4;     // 4.0 MB
    unsigned int* ebs = (unsigned int*)w;     w += (long)SB * CHUNK * 4;         // 6.4 MB
    unsigned short* csr = (unsigned short*)w; w += (long)G_BUCKETS * CAP * 2;    // 6.4 MB
    unsigned short* hsb   = (unsigned short*)w;  w += (long)N_NODES * D_OUT * 2; // 12.8 MB
    unsigned short* featb = (unsigned short*)w;  // 12.8 MB

    // L1: scatter (1280 blocks, long-jobs-first) || weight fuse (128 blocks)
    scatter_fuse_k<<<SB + 128, 256, 0, stream>>>(pe_row, pe_col, seg, ebs,
                                                 W1, Wc, b1, Bp, bf);

    // L2: CSR build (782 blocks, first) || MFMA gemm (782 blocks) — independent roles
    gemm_csr_k    <<<G_BUCKETS + GEMM_BLOCKS, 256, 0, stream>>>(seg, ebs, csr, offs5,
                                                                dinv, x, (const uint4*)Bp,
                                                                bf, hsb);

    // L3: source-tiled aggregation + finalize (dinv applied on the fly)
    aggregate_csr_k<<<AGGB, 256, 0, stream>>>(offs5, csr, (const uint4*)hsb,
                                              dinv, bc, (uint4*)featb);

    // L4: scoring — 4 edges per 16-lane group
    score_k       <<<(QPRED * 16 + 255) / 256, 256, 0, stream>>>(
                      ei_src, ei_dst, (const uint4*)featb, out);
}

// Round 10
// 230.474 us; speedup vs baseline: 1.2152x; 1.0054x over previous
//
#include <hip/hip_runtime.h>

#define N_NODES 50000
#define D_IN 256
#define D_OUT 128
#define N_POS 1600000
#define N_PRED 500000

#define G_BUCKETS 782        // ceil(50000/64) buckets of 64 nodes
#define GPAD 1024
#define SB 1280              // scatter blocks
#define CHUNK 1250           // SB*CHUNK == N_POS exactly
#define SEGP 784             // seg row pitch (padded 782)
#define CAP 4096             // per-bucket segment cap (mean 2048, sigma ~45)
#define GEMM_BLOCKS 782      // (N_NODES+63)/64
#define QPRED 125000         // N_PRED/4 — score_k processes 4 edges per 16-lane group

#define NT 4                 // source tiles: 12500 rows x 256B = 3.2 MB, fits 4 MiB per-XCD L2
#define TSZ 12500
#define NPB 32               // nodes per aggregation block (2 per 16-lane group)
#define AGGB 1563            // ceil(50000/32); ~6252 waves ≈ full residency

typedef __attribute__((ext_vector_type(8))) short short8;
typedef __attribute__((ext_vector_type(4))) float f32x4;

// ---- bf16 helpers (RNE) ----
__device__ __forceinline__ unsigned short f2bf(float f) {
    unsigned int u = __float_as_uint(f);
    u += 0x7FFFu + ((u >> 16) & 1u);
    return (unsigned short)(u >> 16);
}
__device__ __forceinline__ unsigned int pk2(float a, float b) {   // bf16(a) | bf16(b)<<16
    unsigned int ua = __float_as_uint(a), ub = __float_as_uint(b);
    ua += 0x7FFFu + ((ua >> 16) & 1u);
    ub += 0x7FFFu + ((ub >> 16) & 1u);
    return (ua >> 16) | (ub & 0xFFFF0000u);
}
__device__ __forceinline__ float bflo(unsigned int u) { return __uint_as_float(u << 16); }
__device__ __forceinline__ float bfhi(unsigned int u) { return __uint_as_float(u & 0xFFFF0000u); }

__device__ __forceinline__ float dot8(uint4 ua, uint4 ub) {
    return bflo(ua.x) * bflo(ub.x) + bfhi(ua.x) * bfhi(ub.x)
         + bflo(ua.y) * bflo(ub.y) + bfhi(ua.y) * bfhi(ub.y)
         + bflo(ua.z) * bflo(ub.z) + bfhi(ua.z) * bfhi(ub.z)
         + bflo(ua.w) * bflo(ub.w) + bfhi(ua.w) * bfhi(ub.w);
}

// ------- fused launch: blocks [0,SB) bucket-scatter (long jobs first);
//         blocks [SB, SB+128) weight-fuse Wf = W1@Wc into MFMA B-frag + bf = b1@Wc.
//         seg is TRANSPOSED [b][g]: segment-table write is fully coalesced. -------
__global__ __launch_bounds__(256) void scatter_fuse_k(const int* __restrict__ row,
                                                      const int* __restrict__ col,
                                                      unsigned int* __restrict__ seg,
                                                      unsigned int* __restrict__ ebs,
                                                      const float* __restrict__ W1,
                                                      const float* __restrict__ Wc,
                                                      const float* __restrict__ b1,
                                                      unsigned short* __restrict__ Bp,
                                                      float* __restrict__ bf) {
    __shared__ __align__(16) char smem[18432];
    if (blockIdx.x < SB) {
        // ---------------- scatter role ----------------
        int* hist  = (int*)smem;                 // GPAD ints
        int* lofs  = hist + GPAD;                // GPAD ints
        int* fill2 = lofs + GPAD;                // GPAD ints
        int* part  = fill2 + GPAD;               // 256 ints
        unsigned int* stag = (unsigned int*)(part + 256);   // CHUNK u32 (5000 B)
        int t = threadIdx.x;
        int b = blockIdx.x;
        for (int i = t; i < GPAD; i += 256) { hist[i] = 0; fill2[i] = 0; }
        __syncthreads();
        int e0 = b * CHUNK;
        for (int i = t; i < CHUNK; i += 256)
            atomicAdd(&hist[col[e0 + i] >> 6], 1);
        __syncthreads();
        int h[4], p4 = 0;
        #pragma unroll
        for (int i = 0; i < 4; ++i) { h[i] = hist[4 * t + i]; p4 += h[i]; }
        part[t] = p4;
        __syncthreads();
        for (int d = 1; d < 256; d <<= 1) {
            int add = (t >= d) ? part[t - d] : 0;
            __syncthreads();
            part[t] += add;
            __syncthreads();
        }
        int ex = part[t] - p4;
        #pragma unroll
        for (int i = 0; i < 4; ++i) { lofs[4 * t + i] = ex; ex += h[i]; }
        __syncthreads();
        // deterministic segment table (COALESCED: contiguous per block)
        for (int g = t; g < G_BUCKETS; g += 256)
            seg[(long)b * SEGP + g] = (unsigned int)lofs[g] | ((unsigned int)hist[g] << 16);
        for (int i = t; i < CHUNK; i += 256) {
            int c = col[e0 + i];
            int g = c >> 6;
            unsigned int u = (unsigned int)row[e0 + i] | ((unsigned int)(c & 63) << 16);
            int lp = atomicAdd(&fill2[g], 1);
            stag[lofs[g] + lp] = u;
        }
        __syncthreads();
        // coalesced slab write
        for (int i = t; i < CHUNK; i += 256)
            ebs[(long)b * CHUNK + i] = stag[i];
    } else {
        // ---------------- weight-fuse role ----------------
        int gid = (blockIdx.x - SB) * 256 + threadIdx.x;   // 0..32767
        int k = gid >> 7;          // K dim
        int n = gid & 127;         // N dim
        float acc = 0.f;
        #pragma unroll 4
        for (int kk = 0; kk < D_IN; ++kk)
            acc += W1[k * D_IN + kk] * Wc[kk * D_OUT + n];
        int ks = k >> 5, q = (k >> 3) & 3, jj = k & 7;
        int nt = n >> 4, nl = n & 15;
        int lane = q * 16 + nl;
        Bp[(((long)(ks * 8 + nt)) * 64 + lane) * 8 + jj] = f2bf(acc);
        if (gid < D_OUT) {
            float accb = 0.f;
            for (int kk = 0; kk < D_IN; ++kk)
                accb += b1[kk] * Wc[kk * D_OUT + gid];
            bf[gid] = accb;
        }
    }
}

// ------- fused launch #2: blocks [0, G_BUCKETS) = CSR-build role (longer, first);
//         blocks [G_BUCKETS, G_BUCKETS+GEMM_BLOCKS) = MFMA gemm role.
//         CSR bucket index is XCD-swizzled so co-XCD blocks read consecutive
//         seg[b][g..g+15] entries -> each 64B seg line L2-hits 16x. -------
__global__ __launch_bounds__(256) void gemm_csr_k(const unsigned int* __restrict__ seg,
                                                  const unsigned int* __restrict__ ebs,
                                                  unsigned short* __restrict__ csr,
                                                  int* __restrict__ offs5,
                                                  float* __restrict__ dinv,
                                                  const float* __restrict__ x,
                                                  const uint4* __restrict__ Bp,
                                                  const float* __restrict__ bf,
                                                  unsigned short* __restrict__ hsb) {
    __shared__ __align__(16) char smem[28704];
    if (blockIdx.x < G_BUCKETS) {
        // ---------------- CSR-build role ----------------
        unsigned int* stag = (unsigned int*)smem;                 // CAP u32   = 16384 B
        unsigned short* stag2 = (unsigned short*)(smem + 16384);  // CAP u16   =  8192 B
        int* hist = (int*)(smem + 24576);                         // 256 ints
        int* lofs = hist + 256;
        int* fill = lofs + 256;
        int* part = fill + 256;
        __shared__ int scnt;
        int t = threadIdx.x;
        // XCD-bijective bucket swizzle: xcd = B&7 (round-robin dispatch), q=97, r=6
        int B = blockIdx.x;
        int xcd = B & 7, idx = B >> 3;
        int g = (xcd < 6) ? (xcd * 98 + idx) : (588 + (xcd - 6) * 97 + idx);
        int s = g * CAP;
        hist[t] = 0; fill[t] = 0;
        // --- segment scan + gather: thread t owns origin-blocks t+256*k, k=0..4 ---
        const unsigned int* sg = seg + g;
        unsigned int w0 = sg[(long)t * SEGP];
        unsigned int w1 = sg[(long)(t + 256) * SEGP];
        unsigned int w2 = sg[(long)(t + 512) * SEGP];
        unsigned int w3 = sg[(long)(t + 768) * SEGP];
        unsigned int w4 = sg[(long)(t + 1024) * SEGP];
        int c0 = w0 >> 16, c1 = w1 >> 16, c2 = w2 >> 16, c3 = w3 >> 16, c4 = w4 >> 16;
        int lsum = c0 + c1 + c2 + c3 + c4;
        part[t] = lsum;
        __syncthreads();
        for (int d = 1; d < 256; d <<= 1) {
            int add = (t >= d) ? part[t - d] : 0;
            __syncthreads();
            part[t] += add;
            __syncthreads();
        }
        if (t == 255) scnt = part[255];
        int p = part[t] - lsum;
        {
            const unsigned int* e0p = ebs + (long)t * CHUNK + (w0 & 0xFFFFu);
            for (int k = 0; k < c0; ++k) stag[p + k] = e0p[k];
            p += c0;
            const unsigned int* e1p = ebs + (long)(t + 256) * CHUNK + (w1 & 0xFFFFu);
            for (int k = 0; k < c1; ++k) stag[p + k] = e1p[k];
            p += c1;
            const unsigned int* e2p = ebs + (long)(t + 512) * CHUNK + (w2 & 0xFFFFu);
            for (int k = 0; k < c2; ++k) stag[p + k] = e2p[k];
            p += c2;
            const unsigned int* e3p = ebs + (long)(t + 768) * CHUNK + (w3 & 0xFFFFu);
            for (int k = 0; k < c3; ++k) stag[p + k] = e3p[k];
            p += c3;
            const unsigned int* e4p = ebs + (long)(t + 1024) * CHUNK + (w4 & 0xFFFFu);
            for (int k = 0; k < c4; ++k) stag[p + k] = e4p[k];
        }
        __syncthreads();
        int cnt = scnt;
        // --- 256-key histogram (node_low6, src_tile) over the staged bucket ---
        for (int i = t; i < cnt; i += 256) {
            unsigned int u = stag[i];
            int r = u & 0xFFFF;
            int tile = (r >= TSZ) + (r >= 2 * TSZ) + (r >= 3 * TSZ);
            atomicAdd(&hist[((u >> 16) & 63) * NT + tile], 1);
        }
        __syncthreads();
        int hv = hist[t];
        part[t] = hv;
        __syncthreads();
        for (int d = 1; d < 256; d <<= 1) {
            int add = (t >= d) ? part[t - d] : 0;
            __syncthreads();
            part[t] += add;
            __syncthreads();
        }
        lofs[t] = part[t] - hv;
        __syncthreads();
        if (t < 64) {
            int v = g * 64 + t;
            if (v < N_NODES) {
                int b4 = t * NT;
                int cc0 = hist[b4], cc1 = hist[b4 + 1], cc2 = hist[b4 + 2], cc3 = hist[b4 + 3];
                int o0 = s + lofs[b4];
                offs5[v * 5 + 0] = o0;
                offs5[v * 5 + 1] = o0 + cc0;
                offs5[v * 5 + 2] = o0 + cc0 + cc1;
                offs5[v * 5 + 3] = o0 + cc0 + cc1 + cc2;
                offs5[v * 5 + 4] = o0 + cc0 + cc1 + cc2 + cc3;
                dinv[v] = rsqrtf((float)(cc0 + cc1 + cc2 + cc3) + 1.0f);   // +1 self loop
            }
        }
        for (int i = t; i < cnt; i += 256) {
            unsigned int u = stag[i];
            int r = u & 0xFFFF;
            int tile = (r >= TSZ) + (r >= 2 * TSZ) + (r >= 3 * TSZ);
            int key = ((u >> 16) & 63) * NT + tile;
            int lp = atomicAdd(&fill[key], 1);
            stag2[lofs[key] + lp] = (unsigned short)r;
        }
        __syncthreads();
        for (int i = t; i < cnt; i += 256)
            csr[s + i] = stag2[i];
    } else {
        // ---------------- gemm role: h = x@Wf + bf (raw, UNscaled) ----------------
        const int gb   = blockIdx.x - G_BUCKETS;
        const int wave = threadIdx.x >> 6;
        const int lane = threadIdx.x & 63;
        const int q    = lane >> 4;
        const int ml   = lane & 15;
        const int m0   = gb * 64 + wave * 16;

        f32x4 acc[8];
        #pragma unroll
        for (int t = 0; t < 8; ++t) acc[t] = (f32x4){0.f, 0.f, 0.f, 0.f};

        long arow = m0 + ml; if (arow > N_NODES - 1) arow = N_NODES - 1;
        const float* xrow = x + arow * D_IN + q * 8;

        #pragma unroll
        for (int ks = 0; ks < 8; ++ks) {
            float4 xa = *(const float4*)(xrow + ks * 32);
            float4 xb = *(const float4*)(xrow + ks * 32 + 4);
            union { short8 s; unsigned int u[4]; } af;
            af.u[0] = pk2(xa.x, xa.y);
            af.u[1] = pk2(xa.z, xa.w);
            af.u[2] = pk2(xb.x, xb.y);
            af.u[3] = pk2(xb.z, xb.w);
            #pragma unroll
            for (int nt = 0; nt < 8; ++nt) {
                union { uint4 v; short8 s; } bu;
                bu.v = Bp[(long)(ks * 8 + nt) * 64 + lane];
                acc[nt] = __builtin_amdgcn_mfma_f32_16x16x32_bf16(af.s, bu.s, acc[nt], 0, 0, 0);
            }
        }

        unsigned short* o = (unsigned short*)smem + wave * 2048;
        #pragma unroll
        for (int nt = 0; nt < 8; ++nt) {
            float bn = bf[nt * 16 + ml];
            #pragma unroll
            for (int r = 0; r < 4; ++r) {
                float val = acc[nt][r] + bn;
                o[(q * 4 + r) * 128 + nt * 16 + ml] = f2bf(val);
            }
        }
        __syncthreads();
        #pragma unroll
        for (int i = 0; i < 4; ++i) {
            int fb = i * 1024 + lane * 16;
            int v = m0 + (fb >> 8);
            if (v < N_NODES) {
                uint4 val = *(const uint4*)((const char*)o + fb);
                *(uint4*)((char*)hsb + (long)v * 256 + (fb & 255)) = val;
            }
        }
    }
}

// ---- source-tiled aggregation (R3 shape): 16-lane group owns 2 nodes; register
//      accumulators; dinv[r] applied on the fly via fmaf. ----
__global__ __launch_bounds__(256, 8) void aggregate_csr_k(const int* __restrict__ offs5,
                                                          const unsigned short* __restrict__ csr,
                                                          const uint4* __restrict__ hs4,
                                                          const float* __restrict__ dinv,
                                                          const float* __restrict__ bc,
                                                          uint4* __restrict__ feat4) {
    int tid = threadIdx.x;
    int li  = tid & 15;
    int g16 = tid >> 4;                       // 0..15 group id in block
    int v0 = blockIdx.x * NPB + g16 * 2;
    int v1 = v0 + 1;
    bool ok0 = v0 < N_NODES, ok1 = v1 < N_NODES;

    float a0[8] = {0.f, 0.f, 0.f, 0.f, 0.f, 0.f, 0.f, 0.f};
    float a1[8] = {0.f, 0.f, 0.f, 0.f, 0.f, 0.f, 0.f, 0.f};

    #pragma unroll 1
    for (int tt = 0; tt < NT; ++tt) {
        if (ok0) {
            int i  = offs5[v0 * 5 + tt];
            int s1 = offs5[v0 * 5 + tt + 1];
            for (; i + 3 < s1; i += 4) {
                int r0 = csr[i], r1 = csr[i + 1], r2 = csr[i + 2], r3 = csr[i + 3];
                uint4 u0 = hs4[r0 * 16 + li];
                uint4 u1 = hs4[r1 * 16 + li];
                uint4 u2 = hs4[r2 * 16 + li];
                uint4 u3 = hs4[r3 * 16 + li];
                float d0 = dinv[r0], d1 = dinv[r1], d2 = dinv[r2], d3 = dinv[r3];
                a0[0] = fmaf(d0, bflo(u0.x), a0[0]); a0[0] = fmaf(d1, bflo(u1.x), a0[0]);
                a0[0] = fmaf(d2, bflo(u2.x), a0[0]); a0[0] = fmaf(d3, bflo(u3.x), a0[0]);
                a0[1] = fmaf(d0, bfhi(u0.x), a0[1]); a0[1] = fmaf(d1, bfhi(u1.x), a0[1]);
                a0[1] = fmaf(d2, bfhi(u2.x), a0[1]); a0[1] = fmaf(d3, bfhi(u3.x), a0[1]);
                a0[2] = fmaf(d0, bflo(u0.y), a0[2]); a0[2] = fmaf(d1, bflo(u1.y), a0[2]);
                a0[2] = fmaf(d2, bflo(u2.y), a0[2]); a0[2] = fmaf(d3, bflo(u3.y), a0[2]);
                a0[3] = fmaf(d0, bfhi(u0.y), a0[3]); a0[3] = fmaf(d1, bfhi(u1.y), a0[3]);
                a0[3] = fmaf(d2, bfhi(u2.y), a0[3]); a0[3] = fmaf(d3, bfhi(u3.y), a0[3]);
                a0[4] = fmaf(d0, bflo(u0.z), a0[4]); a0[4] = fmaf(d1, bflo(u1.z), a0[4]);
                a0[4] = fmaf(d2, bflo(u2.z), a0[4]); a0[4] = fmaf(d3, bflo(u3.z), a0[4]);
                a0[5] = fmaf(d0, bfhi(u0.z), a0[5]); a0[5] = fmaf(d1, bfhi(u1.z), a0[5]);
                a0[5] = fmaf(d2, bfhi(u2.z), a0[5]); a0[5] = fmaf(d3, bfhi(u3.z), a0[5]);
                a0[6] = fmaf(d0, bflo(u0.w), a0[6]); a0[6] = fmaf(d1, bflo(u1.w), a0[6]);
                a0[6] = fmaf(d2, bflo(u2.w), a0[6]); a0[6] = fmaf(d3, bflo(u3.w), a0[6]);
                a0[7] = fmaf(d0, bfhi(u0.w), a0[7]); a0[7] = fmaf(d1, bfhi(u1.w), a0[7]);
                a0[7] = fmaf(d2, bfhi(u2.w), a0[7]); a0[7] = fmaf(d3, bfhi(u3.w), a0[7]);
            }
            for (; i < s1; ++i) {
                int r = csr[i];
                uint4 u = hs4[r * 16 + li];
                float d = dinv[r];
                a0[0] = fmaf(d, bflo(u.x), a0[0]); a0[1] = fmaf(d, bfhi(u.x), a0[1]);
                a0[2] = fmaf(d, bflo(u.y), a0[2]); a0[3] = fmaf(d, bfhi(u.y), a0[3]);
                a0[4] = fmaf(d, bflo(u.z), a0[4]); a0[5] = fmaf(d, bfhi(u.z), a0[5]);
                a0[6] = fmaf(d, bflo(u.w), a0[6]); a0[7] = fmaf(d, bfhi(u.w), a0[7]);
            }
        }
        if (ok1) {
            int i  = offs5[v1 * 5 + tt];
            int s1 = offs5[v1 * 5 + tt + 1];
            for (; i + 3 < s1; i += 4) {
                int r0 = csr[i], r1 = csr[i + 1], r2 = csr[i + 2], r3 = csr[i + 3];
                uint4 u0 = hs4[r0 * 16 + li];
                uint4 u1 = hs4[r1 * 16 + li];
                uint4 u2 = hs4[r2 * 16 + li];
                uint4 u3 = hs4[r3 * 16 + li];
                float d0 = dinv[r0], d1 = dinv[r1], d2 = dinv[r2], d3 = dinv[r3];
                a1[0] = fmaf(d0, bflo(u0.x), a1[0]); a1[0] = fmaf(d1, bflo(u1.x), a1[0]);
                a1[0] = fmaf(d2, bflo(u2.x), a1[0]); a1[0] = fmaf(d3, bflo(u3.x), a1[0]);
                a1[1] = fmaf(d0, bfhi(u0.x), a1[1]); a1[1] = fmaf(d1, bfhi(u1.x), a1[1]);
                a1[1] = fmaf(d2, bfhi(u2.x), a1[1]); a1[1] = fmaf(d3, bfhi(u3.x), a1[1]);
                a1[2] = fmaf(d0, bflo(u0.y), a1[2]); a1[2] = fmaf(d1, bflo(u1.y), a1[2]);
                a1[2] = fmaf(d2, bflo(u2.y), a1[2]); a1[2] = fmaf(d3, bflo(u3.y), a1[2]);
                a1[3] = fmaf(d0, bfhi(u0.y), a1[3]); a1[3] = fmaf(d1, bfhi(u1.y), a1[3]);
                a1[3] = fmaf(d2, bfhi(u2.y), a1[3]); a1[3] = fmaf(d3, bfhi(u3.y), a1[3]);
                a1[4] = fmaf(d0, bflo(u0.z), a1[4]); a1[4] = fmaf(d1, bflo(u1.z), a1[4]);
                a1[4] = fmaf(d2, bflo(u2.z), a1[4]); a1[4] = fmaf(d3, bflo(u3.z), a1[4]);
                a1[5] = fmaf(d0, bfhi(u0.z), a1[5]); a1[5] = fmaf(d1, bfhi(u1.z), a1[5]);
                a1[5] = fmaf(d2, bfhi(u2.z), a1[5]); a1[5] = fmaf(d3, bfhi(u3.z), a1[5]);
                a1[6] = fmaf(d0, bflo(u0.w), a1[6]); a1[6] = fmaf(d1, bflo(u1.w), a1[6]);
                a1[6] = fmaf(d2, bflo(u2.w), a1[6]); a1[6] = fmaf(d3, bflo(u3.w), a1[6]);
                a1[7] = fmaf(d0, bfhi(u0.w), a1[7]); a1[7] = fmaf(d1, bfhi(u1.w), a1[7]);
                a1[7] = fmaf(d2, bfhi(u2.w), a1[7]); a1[7] = fmaf(d3, bfhi(u3.w), a1[7]);
            }
            for (; i < s1; ++i) {
                int r = csr[i];
                uint4 u = hs4[r * 16 + li];
                float d = dinv[r];
                a1[0] = fmaf(d, bflo(u.x), a1[0]); a1[1] = fmaf(d, bfhi(u.x), a1[1]);
                a1[2] = fmaf(d, bflo(u.y), a1[2]); a1[3] = fmaf(d, bfhi(u.y), a1[3]);
                a1[4] = fmaf(d, bflo(u.z), a1[4]); a1[5] = fmaf(d, bfhi(u.z), a1[5]);
                a1[6] = fmaf(d, bflo(u.w), a1[6]); a1[7] = fmaf(d, bfhi(u.w), a1[7]);
            }
        }
    }
    // finalize: out = dv*(sum + dv*h_self) + bc
    float4 b0 = *(const float4*)(bc + li * 8);
    float4 b1 = *(const float4*)(bc + li * 8 + 4);
    if (ok0) {
        uint4 su = hs4[(long)v0 * 16 + li];
        float dv = dinv[v0];
        float f0 = dv * (a0[0] + dv * bflo(su.x)) + b0.x;
        float f1 = dv * (a0[1] + dv * bfhi(su.x)) + b0.y;
        float f2 = dv * (a0[2] + dv * bflo(su.y)) + b0.z;
        float f3 = dv * (a0[3] + dv * bfhi(su.y)) + b0.w;
        float f4 = dv * (a0[4] + dv * bflo(su.z)) + b1.x;
        float f5 = dv * (a0[5] + dv * bfhi(su.z)) + b1.y;
        float f6 = dv * (a0[6] + dv * bflo(su.w)) + b1.z;
        float f7 = dv * (a0[7] + dv * bfhi(su.w)) + b1.w;
        uint4 o;
        o.x = pk2(f0, f1); o.y = pk2(f2, f3); o.z = pk2(f4, f5); o.w = pk2(f6, f7);
        feat4[(long)v0 * 16 + li] = o;
    }
    if (ok1) {
        uint4 su = hs4[(long)v1 * 16 + li];
        float dv = dinv[v1];
        float f0 = dv * (a1[0] + dv * bflo(su.x)) + b0.x;
        float f1 = dv * (a1[1] + dv * bfhi(su.x)) + b0.y;
        float f2 = dv * (a1[2] + dv * bflo(su.y)) + b0.z;
        float f3 = dv * (a1[3] + dv * bfhi(su.y)) + b0.w;
        float f4 = dv * (a1[4] + dv * bflo(su.z)) + b1.x;
        float f5 = dv * (a1[5] + dv * bfhi(su.z)) + b1.y;
        float f6 = dv * (a1[6] + dv * bflo(su.w)) + b1.z;
        float f7 = dv * (a1[7] + dv * bfhi(su.w)) + b1.w;
        uint4 o;
        o.x = pk2(f0, f1); o.y = pk2(f2, f3); o.z = pk2(f4, f5); o.w = pk2(f6, f7);
        feat4[(long)v1 * 16 + li] = o;
    }
}

// ---------------- logits[e] = dot(feat[src], feat[dst]) — 16 lanes/edge ----------------
__global__ void score_k(const int* __restrict__ src, const int* __restrict__ dst,
                        const uint4* __restrict__ feat4, float* __restrict__ out) {
    int gid = blockIdx.x * blockDim.x + threadIdx.x;
    int e = gid >> 4;
    int c = gid & 15;
    if (e >= QPRED) return;
    int e0 = e, e1 = e + QPRED, e2 = e + 2 * QPRED, e3 = e + 3 * QPRED;
    int a0 = src[e0], b0 = dst[e0];
    int a1 = src[e1], b1 = dst[e1];
    int a2 = src[e2], b2 = dst[e2];
    int a3 = src[e3], b3 = dst[e3];
    uint4 ua0 = feat4[(long)a0 * 16 + c];
    uint4 ub0 = feat4[(long)b0 * 16 + c];
    uint4 ua1 = feat4[(long)a1 * 16 + c];
    uint4 ub1 = feat4[(long)b1 * 16 + c];
    uint4 ua2 = feat4[(long)a2 * 16 + c];
    uint4 ub2 = feat4[(long)b2 * 16 + c];
    uint4 ua3 = feat4[(long)a3 * 16 + c];
    uint4 ub3 = feat4[(long)b3 * 16 + c];
    float p0 = dot8(ua0, ub0);
    float p1 = dot8(ua1, ub1);
    float p2 = dot8(ua2, ub2);
    float p3 = dot8(ua3, ub3);
    #pragma unroll
    for (int m = 8; m; m >>= 1) {
        p0 += __shfl_xor(p0, m, 16);
        p1 += __shfl_xor(p1, m, 16);
        p2 += __shfl_xor(p2, m, 16);
        p3 += __shfl_xor(p3, m, 16);
    }
    if (c == 0) {
        out[e0] = p0;
        out[e1] = p1;
        out[e2] = p2;
        out[e3] = p3;
    }
}

extern "C" void kernel_launch(void* const* d_in, const int* in_sizes, int n_in,
                              void* d_out, int out_size, void* d_ws, size_t ws_size,
                              hipStream_t stream) {
    const float* x   = (const float*)d_in[0];
    const int*   ei  = (const int*)  d_in[1];   // [2, N_PRED]
    const int*   pe  = (const int*)  d_in[2];   // [2, N_POS]
    const float* W1  = (const float*)d_in[3];
    const float* b1  = (const float*)d_in[4];
    const float* Wc  = (const float*)d_in[5];
    const float* bc  = (const float*)d_in[6];
    float* out = (float*)d_out;

    const int* pe_row = pe;            // source
    const int* pe_col = pe + N_POS;    // target (aggregation)
    const int* ei_src = ei;
    const int* ei_dst = ei + N_PRED;

    // workspace layout (16B-aligned blocks)
    char* w = (char*)d_ws;
    unsigned short* Bp = (unsigned short*)w;  w += 32768 * 2;      // 64 KB
    float* bf    = (float*)w;                 w += 128 * 4;
    float* dinv  = (float*)w;                 w += 50000 * 4;
    int*   offs5 = (int*)w;                   w += 50000 * 5 * 4;  // 1 MB
    unsigned int* seg = (unsigned int*)w;     w += (long)SB * SEGP * 4;          // 4.0 MB
    unsigned int* ebs = (unsigned int*)w;     w += (long)SB * CHUNK * 4;         // 6.4 MB
    unsigned short* csr = (unsigned short*)w; w += (long)G_BUCKETS * CAP * 2;    // 6.4 MB
    unsigned short* hsb   = (unsigned short*)w;  w += (long)N_NODES * D_OUT * 2; // 12.8 MB
    unsigned short* featb = (unsigned short*)w;  // 12.8 MB

    // L1: scatter (1280 blocks, long-jobs-first) || weight fuse (128 blocks)
    scatter_fuse_k<<<SB + 128, 256, 0, stream>>>(pe_row, pe_col, seg, ebs,
                                                 W1, Wc, b1, Bp, bf);

    // L2: CSR build (782 blocks, XCD-swizzled, first) || MFMA gemm (782 blocks)
    gemm_csr_k    <<<G_BUCKETS + GEMM_BLOCKS, 256, 0, stream>>>(seg, ebs, csr, offs5,
                                                                dinv, x, (const uint4*)Bp,
                                                                bf, hsb);

    // L3: source-tiled aggregation + finalize (dinv applied on the fly)
    aggregate_csr_k<<<AGGB, 256, 0, stream>>>(offs5, csr, (const uint4*)hsb,
                                              dinv, bc, (uint4*)featb);

    // L4: scoring — 4 edges per 16-lane group
    score_k       <<<(QPRED * 16 + 255) / 256, 256, 0, stream>>>(
                      ei_src, ei_dst, (const uint4*)featb, out);
}